// Round 6
// baseline (230.503 us; speedup 1.0000x reference)
//
#include <hip/hip_runtime.h>
#include <hip/hip_bf16.h>

// Problem constants (from reference)
#define NUM_AUTHOR 16604
#define EMB_D      300
#define BQ         32768      // batch of query nodes
#define NEDGE      1048576    // total edges
// Padded GEMM dims: K = 3*320 = 960 (each 300-dim section padded to 320), N = 320
#define KPAD 960
#define NPAD 320
#define DPAD 320              // padded embedding row (bf16 table)
#define NNODES 29059

// prep_all sub-grids
#define SEG_BLOCKS 4096                   // NEDGE/256
#define PW_BLOCKS  1200                   // NPAD*KPAD/256
#define CE_BLOCKS  18162                  // ceil(NNODES*160/256)

typedef __attribute__((ext_vector_type(8))) short bf16x8;   // 8 bf16 = 4 VGPRs
typedef __attribute__((ext_vector_type(4))) float f32x4;

__device__ __forceinline__ unsigned short f2bf(float f) {
  unsigned int u = __float_as_uint(f);
  u += 0x7fffu + ((u >> 16) & 1u);           // RNE
  return (unsigned short)(u >> 16);
}

// async global->LDS, 16B/lane. LDS dest is wave-uniform base + lane*16.
__device__ __forceinline__ void async_copy16(const void* g, void* lds_base) {
  __builtin_amdgcn_global_load_lds(
      (const __attribute__((address_space(1))) unsigned int*)g,
      (__attribute__((address_space(3))) unsigned int*)lds_base, 16, 0, 0);
}

// ---------------------------------------------------------------------------
// K1 (fused prep): seg_bounds + prep_w + conv_emb in one launch.
__global__ void prep_all(const int* __restrict__ seg, int* __restrict__ start,
                         const float* __restrict__ W1, unsigned short* __restrict__ Wt,
                         const float* __restrict__ emb, unsigned short* __restrict__ embB) {
  int blk = blockIdx.x;
  if (blk < SEG_BLOCKS) {
    // segment boundaries from sorted seg[]
    int i = blk * 256 + threadIdx.x;
    int s = seg[i];
    int prev = (i == 0) ? -1 : seg[i - 1];
    if (s != prev) {
      for (int b = prev + 1; b <= s; ++b) start[b] = i;
    }
    if (i == NEDGE - 1) {
      for (int b = s + 1; b <= BQ; ++b) start[b] = NEDGE;
    }
  } else if (blk < SEG_BLOCKS + PW_BLOCKS) {
    // pack fp32 W1 [300][900] -> bf16 Wt [NPAD][KPAD] (B^T, zero-padded)
    int i = (blk - SEG_BLOCKS) * 256 + threadIdx.x;
    int n = i / KPAD, k = i % KPAD;
    int sec = k / 320, kk = k % 320;
    unsigned short v = 0;
    if (n < 300 && kk < 300) v = f2bf(W1[n * 900 + sec * 300 + kk]);
    Wt[i] = v;
  } else {
    // convert fp32 emb [NNODES][300] -> bf16 embB [NNODES][320] (zero-padded)
    int i = (blk - SEG_BLOCKS - PW_BLOCKS) * 256 + threadIdx.x;  // uint index
    if (i >= NNODES * (DPAD / 2)) return;
    int r = i / (DPAD / 2), cu = i % (DPAD / 2);
    int c = 2 * cu;
    unsigned int lo = 0, hi = 0;
    if (c < EMB_D)     lo = f2bf(emb[(size_t)r * EMB_D + c]);
    if (c + 1 < EMB_D) hi = f2bf(emb[(size_t)r * EMB_D + c + 1]);
    ((unsigned int*)embB)[i] = lo | (hi << 16);
  }
}

// ---------------------------------------------------------------------------
// unpack 4x(2 bf16), accumulate into float2 pairs (pk-add friendly):
// atot += v always; a1 += v when bit (wave-uniform -> scalar branch).
__device__ __forceinline__ void accum8(uint4 p, int bit,
                                       float2* atot, float2* a1) {
  unsigned int pk[4] = {p.x, p.y, p.z, p.w};
  float2 v[4];
  #pragma unroll
  for (int k = 0; k < 4; ++k) {
    v[k].x = __uint_as_float(pk[k] << 16);
    v[k].y = __uint_as_float(pk[k] & 0xffff0000u);
  }
  #pragma unroll
  for (int k = 0; k < 4; ++k) {
    atot[k].x += v[k].x; atot[k].y += v[k].y;
  }
  if (__builtin_amdgcn_readfirstlane(bit)) {
    #pragma unroll
    for (int k = 0; k < 4; ++k) {
      a1[k].x += v[k].x; a1[k].y += v[k].y;
    }
  }
}

// ---------------------------------------------------------------------------
// K2: per-segment mean pooling over bf16 table. One WAVE per query node
// (2 waves / 128-thread block). 64-edge chunks: indices loaded cooperatively,
// type flags via ballot, row offsets broadcast via __shfl, gathers pipelined
// 8-wide. Lane l<40 owns dims [8l,8l+8) (one uint4). type2 = total - type1.
__global__ __launch_bounds__(128) void pool(
    const int* __restrict__ nodes, const int* __restrict__ neighbors,
    const int* __restrict__ start, const unsigned short* __restrict__ embB,
    unsigned short* __restrict__ comb) {
  int b = blockIdx.x * 2 + (threadIdx.x >> 6);
  int l = threadIdx.x & 63;
  int s0 = start[b], s1 = start[b + 1];
  int node = nodes[b];
  int qa = (node < NUM_AUTHOR) ? 1 : 0;
  bool act = (l < 40);
  const unsigned short* ep = embB + 8 * l;   // per-lane column base

  float2 atot[4], a1[4];
  #pragma unroll
  for (int k = 0; k < 4; ++k) {
    atot[k] = make_float2(0.f, 0.f);
    a1[k]   = make_float2(0.f, 0.f);
  }
  int c1 = 0;
  int rem = s1 - s0;

  for (int base = 0; base < rem; base += 64) {
    int cl = min(64, rem - base);
    int idx = neighbors[s0 + base + min(l, cl - 1)];      // coalesced chunk load
    int same = (((idx < NUM_AUTHOR) ? 1 : 0) == qa) ? 1 : 0;
    unsigned long long bal = __ballot(same != 0);
    unsigned long long msk = (cl >= 64) ? ~0ull : ((1ull << cl) - 1ull);
    c1 += __popcll(bal & msk);
    int off = idx * DPAD;                                  // element offset

    int j2 = 0;
    for (; j2 + 8 <= cl; j2 += 8) {
      int o[8];
      #pragma unroll
      for (int q = 0; q < 8; ++q) o[q] = __shfl(off, j2 + q);
      if (act) {
        uint4 p[8];
        #pragma unroll
        for (int q = 0; q < 8; ++q) p[q] = *(const uint4*)(ep + o[q]);
        #pragma unroll
        for (int q = 0; q < 8; ++q)
          accum8(p[q], (int)((bal >> (j2 + q)) & 1), atot, a1);
      }
    }
    for (; j2 < cl; ++j2) {
      int o = __shfl(off, j2);
      if (act) {
        uint4 p = *(const uint4*)(ep + o);
        accum8(p, (int)((bal >> j2) & 1), atot, a1);
      }
    }
  }

  int c2 = rem - c1;
  if (!act) return;

  uint4 selfv = *(const uint4*)(embB + (size_t)node * DPAD + 8 * l);
  float r1 = c1 ? 1.0f / (float)c1 : 0.0f;
  float r2 = c2 ? 1.0f / (float)c2 : 0.0f;
  unsigned int o1[4], o2[4];
  #pragma unroll
  for (int k = 0; k < 4; ++k) {
    float t1lo = c1 ? a1[k].x * r1 : 1.0f;
    float t1hi = c1 ? a1[k].y * r1 : 1.0f;
    float t2lo = c2 ? (atot[k].x - a1[k].x) * r2 : 1.0f;
    float t2hi = c2 ? (atot[k].y - a1[k].y) * r2 : 1.0f;
    o1[k] = (unsigned int)f2bf(t1lo) | ((unsigned int)f2bf(t1hi) << 16);
    o2[k] = (unsigned int)f2bf(t2lo) | ((unsigned int)f2bf(t2hi) << 16);
  }
  uint4* crow = (uint4*)(comb + (size_t)b * KPAD);   // 120 uint4 per row
  crow[l]      = selfv;                               // self section
  crow[40 + l] = (uint4){o1[0], o1[1], o1[2], o1[3]}; // t1 section
  crow[80 + l] = (uint4){o2[0], o2[1], o2[2], o2[3]}; // t2 section
}

// ---------------------------------------------------------------------------
// K3: GEMM  out[32768][300] = comb[32768][960](bf16) * Wt^T + b1, fp32 out.
// Block tile 64(M) x 160(N) x BK=96 -> 10 K-iterations (was 30). Per iter each
// wave issues ~11 independent global_load_lds (A:12 + B:30 chunks over 4
// waves) -> enough MLP to cover the ~900-cyc HBM miss latency, and 3x fewer
// vmcnt(0)+barrier drains. LDS 42 KB -> 3 blocks/CU. 4 waves 2x2, wave tile
// 32x80, 30 MFMA 16x16x32 per iter.
__global__ __launch_bounds__(256) void gemm(
    const unsigned short* __restrict__ A,    // comb [BQ][KPAD] bf16
    const unsigned short* __restrict__ Bt,   // Wt   [NPAD][KPAD] bf16
    const float* __restrict__ b1,
    float* __restrict__ out) {
  __shared__ __align__(16) unsigned short As[64 * 96];    // 12 KB [row][k]
  __shared__ __align__(16) unsigned short Bs[160 * 96];   // 30 KB [n][k]

  int tid  = threadIdx.x;
  int lane = tid & 63;
  int w    = tid >> 6;
  int quad = lane >> 4;
  int l16  = lane & 15;
  int bm = blockIdx.x >> 1;     // 512 row-tiles of 64
  int bn = blockIdx.x & 1;      // 2 col-tiles of 160
  int wm = w >> 1, wn = w & 1;

  f32x4 acc[2][5];
  for (int i = 0; i < 2; ++i)
    for (int j = 0; j < 5; ++j)
      acc[i][j] = (f32x4){0.f, 0.f, 0.f, 0.f};

  const size_t Abase = (size_t)bm * 64 * KPAD;
  const size_t Bbase = (size_t)bn * 160 * KPAD;

  for (int kt = 0; kt < KPAD / 96; ++kt) {
    int k0 = kt * 96;
    __syncthreads();  // previous iteration's ds_reads done before overwrite
    // Stage A: 12 chunks of 64 lanes x 16B. flat8 = c*64+lane indexes 8-elem
    // groups: row = flat8/12, k-offset = (flat8%12)*8 within the 96-wide tile.
    for (int c = w; c < 12; c += 4) {
      int flat = c * 64 + lane;
      int row = flat / 12, kq = flat % 12;
      const unsigned short* g = A + Abase + (size_t)row * KPAD + k0 + kq * 8;
      async_copy16(g, (char*)As + c * 1024);
    }
    // Stage B^T: 30 chunks
    for (int c = w; c < 30; c += 4) {
      int flat = c * 64 + lane;
      int nrow = flat / 12, kq = flat % 12;
      const unsigned short* g = Bt + Bbase + (size_t)nrow * KPAD + k0 + kq * 8;
      async_copy16(g, (char*)Bs + c * 1024);
    }
    __syncthreads();  // drains vmcnt for global_load_lds

    #pragma unroll
    for (int ks = 0; ks < 3; ++ks) {
      bf16x8 af[2], bf[5];
      for (int rt = 0; rt < 2; ++rt)
        af[rt] = *(const bf16x8*)&As[(wm * 32 + rt * 16 + l16) * 96 + ks * 32 + quad * 8];
      for (int ct = 0; ct < 5; ++ct)
        bf[ct] = *(const bf16x8*)&Bs[(wn * 80 + ct * 16 + l16) * 96 + ks * 32 + quad * 8];
      for (int rt = 0; rt < 2; ++rt)
        for (int ct = 0; ct < 5; ++ct)
          acc[rt][ct] = __builtin_amdgcn_mfma_f32_16x16x32_bf16(
              af[rt], bf[ct], acc[rt][ct], 0, 0, 0);
    }
  }

  // Epilogue: C[m][n], m = m0+rt*16+quad*4+r, n = n0+ct*16+l16
  int m0 = bm * 64 + wm * 32;
  int n0 = bn * 160 + wn * 80;
  for (int ct = 0; ct < 5; ++ct) {
    int n = n0 + ct * 16 + l16;
    if (n >= 300) continue;
    float bias = b1[n];
    for (int rt = 0; rt < 2; ++rt) {
      int m = m0 + rt * 16 + quad * 4;
      for (int r = 0; r < 4; ++r)
        out[(size_t)(m + r) * 300 + n] = acc[rt][ct][r] + bias;
    }
  }
}

// ---------------------------------------------------------------------------
// Fallback pool (ws too small for bf16 table): round-2 fp32 pool.
__global__ __launch_bounds__(128) void pool_f32(
    const int* __restrict__ nodes, const int* __restrict__ neighbors,
    const int* __restrict__ start, const float* __restrict__ emb,
    unsigned short* __restrict__ comb) {
  int b = blockIdx.x;
  int t = threadIdx.x;
  if (t >= 80) return;
  int s0 = start[b], s1 = start[b + 1];
  int node = nodes[b];
  int qa = (node < NUM_AUTHOR) ? 1 : 0;
  bool act = (t < 75);
  float a1x = 0.f, a1y = 0.f, a1z = 0.f, a1w = 0.f;
  float a2x = 0.f, a2y = 0.f, a2z = 0.f, a2w = 0.f;
  int c1 = 0;
  #pragma unroll 2
  for (int j = s0; j < s1; ++j) {
    int nb = neighbors[j];
    int fl = (((nb < NUM_AUTHOR) ? 1 : 0) == qa) ? 1 : 0;
    c1 += fl;
    if (act) {
      const float4 v = *(const float4*)(emb + (size_t)nb * EMB_D + 4 * t);
      float w = fl ? 1.0f : 0.0f;
      float u = 1.0f - w;
      a1x += w * v.x; a1y += w * v.y; a1z += w * v.z; a1w += w * v.w;
      a2x += u * v.x; a2y += u * v.y; a2z += u * v.z; a2w += u * v.w;
    }
  }
  int c2 = (s1 - s0) - c1;
  unsigned int ps0 = 0, ps1 = 0, p10 = 0, p11 = 0, p20 = 0, p21 = 0;
  if (act) {
    const float4 sv = *(const float4*)(emb + (size_t)node * EMB_D + 4 * t);
    float r1 = c1 ? 1.0f / (float)c1 : 0.0f;
    float r2 = c2 ? 1.0f / (float)c2 : 0.0f;
    float t1x = c1 ? a1x * r1 : 1.0f, t1y = c1 ? a1y * r1 : 1.0f;
    float t1z = c1 ? a1z * r1 : 1.0f, t1w = c1 ? a1w * r1 : 1.0f;
    float t2x = c2 ? a2x * r2 : 1.0f, t2y = c2 ? a2y * r2 : 1.0f;
    float t2z = c2 ? a2z * r2 : 1.0f, t2w = c2 ? a2w * r2 : 1.0f;
    ps0 = (unsigned int)f2bf(sv.x) | ((unsigned int)f2bf(sv.y) << 16);
    ps1 = (unsigned int)f2bf(sv.z) | ((unsigned int)f2bf(sv.w) << 16);
    p10 = (unsigned int)f2bf(t1x) | ((unsigned int)f2bf(t1y) << 16);
    p11 = (unsigned int)f2bf(t1z) | ((unsigned int)f2bf(t1w) << 16);
    p20 = (unsigned int)f2bf(t2x) | ((unsigned int)f2bf(t2y) << 16);
    p21 = (unsigned int)f2bf(t2z) | ((unsigned int)f2bf(t2w) << 16);
  }
  unsigned int* crow = (unsigned int*)(comb + (size_t)b * KPAD);
  crow[2 * t]       = ps0;  crow[2 * t + 1]       = ps1;
  crow[160 + 2 * t] = p10;  crow[160 + 2 * t + 1] = p11;
  crow[320 + 2 * t] = p20;  crow[320 + 2 * t + 1] = p21;
}

__global__ void seg_bounds_only(const int* __restrict__ seg, int* __restrict__ start) {
  int i = blockIdx.x * 256 + threadIdx.x;
  if (i >= NEDGE) return;
  int s = seg[i];
  int prev = (i == 0) ? -1 : seg[i - 1];
  if (s != prev) for (int b = prev + 1; b <= s; ++b) start[b] = i;
  if (i == NEDGE - 1) for (int b = s + 1; b <= BQ; ++b) start[b] = NEDGE;
}
__global__ void prep_w_only(const float* __restrict__ W1, unsigned short* __restrict__ Wt) {
  int i = blockIdx.x * 256 + threadIdx.x;
  if (i >= NPAD * KPAD) return;
  int n = i / KPAD, k = i % KPAD;
  int sec = k / 320, kk = k % 320;
  unsigned short v = 0;
  if (n < 300 && kk < 300) v = f2bf(W1[n * 900 + sec * 300 + kk]);
  Wt[i] = v;
}

// ---------------------------------------------------------------------------
extern "C" void kernel_launch(void* const* d_in, const int* in_sizes, int n_in,
                              void* d_out, int out_size, void* d_ws, size_t ws_size,
                              hipStream_t stream) {
  const int* nodes     = (const int*)d_in[0];
  const int* seg       = (const int*)d_in[1];
  const int* neighbors = (const int*)d_in[2];
  const float* emb     = (const float*)d_in[3];
  const float* W1      = (const float*)d_in[4];
  const float* b1      = (const float*)d_in[5];
  float* out           = (float*)d_out;

  // Workspace layout:
  //   [0, 131584)       start[BQ+1] int
  //   [131584, 746496)  Wt [320][960] bf16 (614400 B + pad)
  //   [746496, 63661056)            comb [32768][960] bf16
  //   [63661056, 82258816)          embB [29059][320] bf16
  char* ws = (char*)d_ws;
  int* start           = (int*)ws;
  unsigned short* Wt   = (unsigned short*)(ws + 131584);
  unsigned short* comb = (unsigned short*)(ws + 746496);
  unsigned short* embB = (unsigned short*)(ws + 63661056);
  const size_t WS_NEEDED = 82258816;

  if (ws_size >= WS_NEEDED) {
    prep_all<<<SEG_BLOCKS + PW_BLOCKS + CE_BLOCKS, 256, 0, stream>>>(
        seg, start, W1, Wt, emb, embB);
    pool<<<BQ / 2, 128, 0, stream>>>(nodes, neighbors, start, embB, comb);
  } else {
    seg_bounds_only<<<SEG_BLOCKS, 256, 0, stream>>>(seg, start);
    prep_w_only<<<PW_BLOCKS, 256, 0, stream>>>(W1, Wt);
    pool_f32<<<BQ, 128, 0, stream>>>(nodes, neighbors, start, emb, comb);
  }
  gemm<<<1024, 256, 0, stream>>>(comb, Wt, b1, out);
}

// Round 7
// 227.819 us; speedup vs baseline: 1.0118x; 1.0118x over previous
//
#include <hip/hip_runtime.h>
#include <hip/hip_bf16.h>

// Problem constants (from reference)
#define NUM_AUTHOR 16604
#define EMB_D      300
#define BQ         32768      // batch of query nodes
#define NEDGE      1048576    // total edges
// Padded GEMM dims: K = 3*320 = 960 (each 300-dim section padded to 320), N = 320
#define KPAD 960
#define NPAD 320
#define DPAD 320              // padded embedding row (bf16 table)
#define NNODES 29059

// prep_all sub-grids
#define SEG_BLOCKS 4096                   // NEDGE/256
#define PW_BLOCKS  1200                   // NPAD*KPAD/256
#define CE_BLOCKS  4541                   // ceil(NNODES*40 uint4 / 256)

typedef __attribute__((ext_vector_type(8))) short bf16x8;   // 8 bf16 = 4 VGPRs
typedef __attribute__((ext_vector_type(4))) float f32x4;

__device__ __forceinline__ unsigned short f2bf(float f) {
  unsigned int u = __float_as_uint(f);
  u += 0x7fffu + ((u >> 16) & 1u);           // RNE
  return (unsigned short)(u >> 16);
}

// async global->LDS, 16B/lane. LDS dest is wave-uniform base + lane*16.
__device__ __forceinline__ void async_copy16(const void* g, void* lds_base) {
  __builtin_amdgcn_global_load_lds(
      (const __attribute__((address_space(1))) unsigned int*)g,
      (__attribute__((address_space(3))) unsigned int*)lds_base, 16, 0, 0);
}

// ---------------------------------------------------------------------------
// K1 (fused prep): seg_bounds + prep_w + conv_emb in one launch.
__global__ void prep_all(const int* __restrict__ seg, int* __restrict__ start,
                         const float* __restrict__ W1, unsigned short* __restrict__ Wt,
                         const float* __restrict__ emb, unsigned short* __restrict__ embB) {
  int blk = blockIdx.x;
  if (blk < SEG_BLOCKS) {
    // segment boundaries from sorted seg[]
    int i = blk * 256 + threadIdx.x;
    int s = seg[i];
    int prev = (i == 0) ? -1 : seg[i - 1];
    if (s != prev) {
      for (int b = prev + 1; b <= s; ++b) start[b] = i;
    }
    if (i == NEDGE - 1) {
      for (int b = s + 1; b <= BQ; ++b) start[b] = NEDGE;
    }
  } else if (blk < SEG_BLOCKS + PW_BLOCKS) {
    // pack fp32 W1 [300][900] -> bf16 Wt [NPAD][KPAD] (B^T, zero-padded)
    int i = (blk - SEG_BLOCKS) * 256 + threadIdx.x;
    int n = i / KPAD, k = i % KPAD;
    int sec = k / 320, kk = k % 320;
    unsigned short v = 0;
    if (n < 300 && kk < 300) v = f2bf(W1[n * 900 + sec * 300 + kk]);
    Wt[i] = v;
  } else {
    // convert fp32 emb [NNODES][300] -> bf16 embB [NNODES][320], uint4 units
    int i = (blk - SEG_BLOCKS - PW_BLOCKS) * 256 + threadIdx.x;  // uint4 index
    if (i >= NNODES * 40) return;
    int r = i / 40, q = i % 40;          // q: 8-elem granule within row
    const float* src = emb + (size_t)r * EMB_D + q * 8;
    unsigned int u[4] = {0, 0, 0, 0};
    if (q < 37) {                         // full 8 elems in-bounds (296 max)
      float4 v0 = *(const float4*)src;
      float4 v1 = *(const float4*)(src + 4);
      u[0] = (unsigned int)f2bf(v0.x) | ((unsigned int)f2bf(v0.y) << 16);
      u[1] = (unsigned int)f2bf(v0.z) | ((unsigned int)f2bf(v0.w) << 16);
      u[2] = (unsigned int)f2bf(v1.x) | ((unsigned int)f2bf(v1.y) << 16);
      u[3] = (unsigned int)f2bf(v1.z) | ((unsigned int)f2bf(v1.w) << 16);
    } else if (q == 37) {                 // elems 296..299 valid, rest pad
      float4 v0 = *(const float4*)src;
      u[0] = (unsigned int)f2bf(v0.x) | ((unsigned int)f2bf(v0.y) << 16);
      u[1] = (unsigned int)f2bf(v0.z) | ((unsigned int)f2bf(v0.w) << 16);
    }
    ((uint4*)embB)[i] = (uint4){u[0], u[1], u[2], u[3]};
  }
}

// ---------------------------------------------------------------------------
// unpack 4x(2 bf16), accumulate into float2 pairs (pk-add friendly):
// atot += v always; a1 += v when bit (wave-uniform -> scalar branch).
__device__ __forceinline__ void accum8(uint4 p, int bit,
                                       float2* atot, float2* a1) {
  unsigned int pk[4] = {p.x, p.y, p.z, p.w};
  float2 v[4];
  #pragma unroll
  for (int k = 0; k < 4; ++k) {
    v[k].x = __uint_as_float(pk[k] << 16);
    v[k].y = __uint_as_float(pk[k] & 0xffff0000u);
  }
  #pragma unroll
  for (int k = 0; k < 4; ++k) {
    atot[k].x += v[k].x; atot[k].y += v[k].y;
  }
  if (__builtin_amdgcn_readfirstlane(bit)) {
    #pragma unroll
    for (int k = 0; k < 4; ++k) {
      a1[k].x += v[k].x; a1[k].y += v[k].y;
    }
  }
}

// ---------------------------------------------------------------------------
// K2: per-segment mean pooling over bf16 table. One WAVE per query node
// (2 waves / 128-thread block). 64-edge chunks: indices loaded cooperatively,
// type flags via ballot, row offsets broadcast via __shfl, gathers pipelined
// 8-wide. Lane l<40 owns dims [8l,8l+8) (one uint4). type2 = total - type1.
__global__ __launch_bounds__(128) void pool(
    const int* __restrict__ nodes, const int* __restrict__ neighbors,
    const int* __restrict__ start, const unsigned short* __restrict__ embB,
    unsigned short* __restrict__ comb) {
  int b = blockIdx.x * 2 + (threadIdx.x >> 6);
  int l = threadIdx.x & 63;
  int s0 = start[b], s1 = start[b + 1];
  int node = nodes[b];
  int qa = (node < NUM_AUTHOR) ? 1 : 0;
  bool act = (l < 40);
  const unsigned short* ep = embB + 8 * l;   // per-lane column base

  float2 atot[4], a1[4];
  #pragma unroll
  for (int k = 0; k < 4; ++k) {
    atot[k] = make_float2(0.f, 0.f);
    a1[k]   = make_float2(0.f, 0.f);
  }
  int c1 = 0;
  int rem = s1 - s0;

  for (int base = 0; base < rem; base += 64) {
    int cl = min(64, rem - base);
    int idx = neighbors[s0 + base + min(l, cl - 1)];      // coalesced chunk load
    int same = (((idx < NUM_AUTHOR) ? 1 : 0) == qa) ? 1 : 0;
    unsigned long long bal = __ballot(same != 0);
    unsigned long long msk = (cl >= 64) ? ~0ull : ((1ull << cl) - 1ull);
    c1 += __popcll(bal & msk);
    int off = idx * DPAD;                                  // element offset

    int j2 = 0;
    for (; j2 + 8 <= cl; j2 += 8) {
      int o[8];
      #pragma unroll
      for (int q = 0; q < 8; ++q) o[q] = __shfl(off, j2 + q);
      if (act) {
        uint4 p[8];
        #pragma unroll
        for (int q = 0; q < 8; ++q) p[q] = *(const uint4*)(ep + o[q]);
        #pragma unroll
        for (int q = 0; q < 8; ++q)
          accum8(p[q], (int)((bal >> (j2 + q)) & 1), atot, a1);
      }
    }
    for (; j2 < cl; ++j2) {
      int o = __shfl(off, j2);
      if (act) {
        uint4 p = *(const uint4*)(ep + o);
        accum8(p, (int)((bal >> j2) & 1), atot, a1);
      }
    }
  }

  int c2 = rem - c1;
  if (!act) return;

  uint4 selfv = *(const uint4*)(embB + (size_t)node * DPAD + 8 * l);
  float r1 = c1 ? 1.0f / (float)c1 : 0.0f;
  float r2 = c2 ? 1.0f / (float)c2 : 0.0f;
  unsigned int o1[4], o2[4];
  #pragma unroll
  for (int k = 0; k < 4; ++k) {
    float t1lo = c1 ? a1[k].x * r1 : 1.0f;
    float t1hi = c1 ? a1[k].y * r1 : 1.0f;
    float t2lo = c2 ? (atot[k].x - a1[k].x) * r2 : 1.0f;
    float t2hi = c2 ? (atot[k].y - a1[k].y) * r2 : 1.0f;
    o1[k] = (unsigned int)f2bf(t1lo) | ((unsigned int)f2bf(t1hi) << 16);
    o2[k] = (unsigned int)f2bf(t2lo) | ((unsigned int)f2bf(t2hi) << 16);
  }
  uint4* crow = (uint4*)(comb + (size_t)b * KPAD);   // 120 uint4 per row
  crow[l]      = selfv;                               // self section
  crow[40 + l] = (uint4){o1[0], o1[1], o1[2], o1[3]}; // t1 section
  crow[80 + l] = (uint4){o2[0], o2[1], o2[2], o2[3]}; // t2 section
}

// ---------------------------------------------------------------------------
// K3: GEMM  out[32768][300] = comb[32768][960](bf16) * Wt^T + b1, fp32 out.
// Block tile 64(M) x 160(N), BK=64, DOUBLE-BUFFERED single-barrier K-loop:
// per iter: barrier -> issue stage(kt+1) -> compute(kt). The vmcnt(0) drain at
// the next barrier is overlapped by compute. XOR swizzle (granule g = gi ^
// (row&7), applied via the lane's GLOBAL fetch address at stage time) spreads
// ds_read_b128 across all 32 banks (2-way max = free). LDS 56 KB -> 2
// blocks/CU. 4 waves 2x2, wave tile 32x80, 20 MFMA 16x16x32 per iter.
__global__ __launch_bounds__(256) void gemm(
    const unsigned short* __restrict__ A,    // comb [BQ][KPAD] bf16
    const unsigned short* __restrict__ Bt,   // Wt   [NPAD][KPAD] bf16
    const float* __restrict__ b1,
    float* __restrict__ out) {
  __shared__ __align__(16) unsigned short As[2][64 * 64];   // 8 KB each
  __shared__ __align__(16) unsigned short Bs[2][160 * 64];  // 20 KB each

  int tid  = threadIdx.x;
  int lane = tid & 63;
  int w    = tid >> 6;
  int quad = lane >> 4;
  int l16  = lane & 15;
  int bm = blockIdx.x >> 1;     // 512 row-tiles of 64
  int bn = blockIdx.x & 1;      // 2 col-tiles of 160
  int wm = w >> 1, wn = w & 1;

  f32x4 acc[2][5];
  for (int i = 0; i < 2; ++i)
    for (int j = 0; j < 5; ++j)
      acc[i][j] = (f32x4){0.f, 0.f, 0.f, 0.f};

  const size_t Abase = (size_t)bm * 64 * KPAD;
  const size_t Bbase = (size_t)bn * 160 * KPAD;

  auto stage = [&](int kt, int buf) {
    int k0 = kt * 64;
    // A: 8 chunks of 64 lanes x 16B. LDS slot (row, g) holds global granule
    // g ^ (row & 7) -> conflict-free ds_read later.
    for (int c = w; c < 8; c += 4) {
      int flat = c * 64 + lane;
      int row = flat >> 3, g = flat & 7;
      int kq = g ^ (row & 7);
      const unsigned short* gp = A + Abase + (size_t)row * KPAD + k0 + kq * 8;
      async_copy16(gp, (char*)&As[buf][0] + c * 1024);
    }
    // B^T: 20 chunks
    for (int c = w; c < 20; c += 4) {
      int flat = c * 64 + lane;
      int row = flat >> 3, g = flat & 7;
      int kq = g ^ (row & 7);
      const unsigned short* gp = Bt + Bbase + (size_t)row * KPAD + k0 + kq * 8;
      async_copy16(gp, (char*)&Bs[buf][0] + c * 1024);
    }
  };

  stage(0, 0);
  for (int kt = 0; kt < KPAD / 64; ++kt) {
    int cur = kt & 1;
    __syncthreads();                    // drains stage(kt); syncs buffers
    if (kt + 1 < KPAD / 64) stage(kt + 1, cur ^ 1);
    #pragma unroll
    for (int ks = 0; ks < 2; ++ks) {
      int gi = ks * 4 + quad;           // k-granule index within BK=64
      bf16x8 af[2], bf[5];
      #pragma unroll
      for (int rt = 0; rt < 2; ++rt) {
        int row = wm * 32 + rt * 16 + l16;
        af[rt] = *(const bf16x8*)&As[cur][row * 64 + ((gi ^ (row & 7)) << 3)];
      }
      #pragma unroll
      for (int ct = 0; ct < 5; ++ct) {
        int row = wn * 80 + ct * 16 + l16;
        bf[ct] = *(const bf16x8*)&Bs[cur][row * 64 + ((gi ^ (row & 7)) << 3)];
      }
      #pragma unroll
      for (int rt = 0; rt < 2; ++rt)
        #pragma unroll
        for (int ct = 0; ct < 5; ++ct)
          acc[rt][ct] = __builtin_amdgcn_mfma_f32_16x16x32_bf16(
              af[rt], bf[ct], acc[rt][ct], 0, 0, 0);
    }
  }

  // Epilogue: C[m][n], m = m0+rt*16+quad*4+r, n = n0+ct*16+l16
  int m0 = bm * 64 + wm * 32;
  int n0 = bn * 160 + wn * 80;
  for (int ct = 0; ct < 5; ++ct) {
    int n = n0 + ct * 16 + l16;
    if (n >= 300) continue;
    float bias = b1[n];
    for (int rt = 0; rt < 2; ++rt) {
      int m = m0 + rt * 16 + quad * 4;
      for (int r = 0; r < 4; ++r)
        out[(size_t)(m + r) * 300 + n] = acc[rt][ct][r] + bias;
    }
  }
}

// ---------------------------------------------------------------------------
// Fallback pool (ws too small for bf16 table): round-2 fp32 pool.
__global__ __launch_bounds__(128) void pool_f32(
    const int* __restrict__ nodes, const int* __restrict__ neighbors,
    const int* __restrict__ start, const float* __restrict__ emb,
    unsigned short* __restrict__ comb) {
  int b = blockIdx.x;
  int t = threadIdx.x;
  if (t >= 80) return;
  int s0 = start[b], s1 = start[b + 1];
  int node = nodes[b];
  int qa = (node < NUM_AUTHOR) ? 1 : 0;
  bool act = (t < 75);
  float a1x = 0.f, a1y = 0.f, a1z = 0.f, a1w = 0.f;
  float a2x = 0.f, a2y = 0.f, a2z = 0.f, a2w = 0.f;
  int c1 = 0;
  #pragma unroll 2
  for (int j = s0; j < s1; ++j) {
    int nb = neighbors[j];
    int fl = (((nb < NUM_AUTHOR) ? 1 : 0) == qa) ? 1 : 0;
    c1 += fl;
    if (act) {
      const float4 v = *(const float4*)(emb + (size_t)nb * EMB_D + 4 * t);
      float w = fl ? 1.0f : 0.0f;
      float u = 1.0f - w;
      a1x += w * v.x; a1y += w * v.y; a1z += w * v.z; a1w += w * v.w;
      a2x += u * v.x; a2y += u * v.y; a2z += u * v.z; a2w += u * v.w;
    }
  }
  int c2 = (s1 - s0) - c1;
  unsigned int ps0 = 0, ps1 = 0, p10 = 0, p11 = 0, p20 = 0, p21 = 0;
  if (act) {
    const float4 sv = *(const float4*)(emb + (size_t)node * EMB_D + 4 * t);
    float r1 = c1 ? 1.0f / (float)c1 : 0.0f;
    float r2 = c2 ? 1.0f / (float)c2 : 0.0f;
    float t1x = c1 ? a1x * r1 : 1.0f, t1y = c1 ? a1y * r1 : 1.0f;
    float t1z = c1 ? a1z * r1 : 1.0f, t1w = c1 ? a1w * r1 : 1.0f;
    float t2x = c2 ? a2x * r2 : 1.0f, t2y = c2 ? a2y * r2 : 1.0f;
    float t2z = c2 ? a2z * r2 : 1.0f, t2w = c2 ? a2w * r2 : 1.0f;
    ps0 = (unsigned int)f2bf(sv.x) | ((unsigned int)f2bf(sv.y) << 16);
    ps1 = (unsigned int)f2bf(sv.z) | ((unsigned int)f2bf(sv.w) << 16);
    p10 = (unsigned int)f2bf(t1x) | ((unsigned int)f2bf(t1y) << 16);
    p11 = (unsigned int)f2bf(t1z) | ((unsigned int)f2bf(t1w) << 16);
    p20 = (unsigned int)f2bf(t2x) | ((unsigned int)f2bf(t2y) << 16);
    p21 = (unsigned int)f2bf(t2z) | ((unsigned int)f2bf(t2w) << 16);
  }
  unsigned int* crow = (unsigned int*)(comb + (size_t)b * KPAD);
  crow[2 * t]       = ps0;  crow[2 * t + 1]       = ps1;
  crow[160 + 2 * t] = p10;  crow[160 + 2 * t + 1] = p11;
  crow[320 + 2 * t] = p20;  crow[320 + 2 * t + 1] = p21;
}

__global__ void seg_bounds_only(const int* __restrict__ seg, int* __restrict__ start) {
  int i = blockIdx.x * 256 + threadIdx.x;
  if (i >= NEDGE) return;
  int s = seg[i];
  int prev = (i == 0) ? -1 : seg[i - 1];
  if (s != prev) for (int b = prev + 1; b <= s; ++b) start[b] = i;
  if (i == NEDGE - 1) for (int b = s + 1; b <= BQ; ++b) start[b] = NEDGE;
}
__global__ void prep_w_only(const float* __restrict__ W1, unsigned short* __restrict__ Wt) {
  int i = blockIdx.x * 256 + threadIdx.x;
  if (i >= NPAD * KPAD) return;
  int n = i / KPAD, k = i % KPAD;
  int sec = k / 320, kk = k % 320;
  unsigned short v = 0;
  if (n < 300 && kk < 300) v = f2bf(W1[n * 900 + sec * 300 + kk]);
  Wt[i] = v;
}

// ---------------------------------------------------------------------------
extern "C" void kernel_launch(void* const* d_in, const int* in_sizes, int n_in,
                              void* d_out, int out_size, void* d_ws, size_t ws_size,
                              hipStream_t stream) {
  const int* nodes     = (const int*)d_in[0];
  const int* seg       = (const int*)d_in[1];
  const int* neighbors = (const int*)d_in[2];
  const float* emb     = (const float*)d_in[3];
  const float* W1      = (const float*)d_in[4];
  const float* b1      = (const float*)d_in[5];
  float* out           = (float*)d_out;

  // Workspace layout:
  //   [0, 131584)       start[BQ+1] int
  //   [131584, 746496)  Wt [320][960] bf16 (614400 B + pad)
  //   [746496, 63661056)            comb [32768][960] bf16
  //   [63661056, 82258816)          embB [29059][320] bf16
  char* ws = (char*)d_ws;
  int* start           = (int*)ws;
  unsigned short* Wt   = (unsigned short*)(ws + 131584);
  unsigned short* comb = (unsigned short*)(ws + 746496);
  unsigned short* embB = (unsigned short*)(ws + 63661056);
  const size_t WS_NEEDED = 82258816;

  if (ws_size >= WS_NEEDED) {
    prep_all<<<SEG_BLOCKS + PW_BLOCKS + CE_BLOCKS, 256, 0, stream>>>(
        seg, start, W1, Wt, emb, embB);
    pool<<<BQ / 2, 128, 0, stream>>>(nodes, neighbors, start, embB, comb);
  } else {
    seg_bounds_only<<<SEG_BLOCKS, 256, 0, stream>>>(seg, start);
    prep_w_only<<<PW_BLOCKS, 256, 0, stream>>>(W1, Wt);
    pool_f32<<<BQ, 128, 0, stream>>>(nodes, neighbors, start, emb, comb);
  }
  gemm<<<1024, 256, 0, stream>>>(comb, Wt, b1, out);
}